// Round 1
// baseline (546.031 us; speedup 1.0000x reference)
//
#include <hip/hip_runtime.h>

// RNN scan: T=750 sequential steps over state x[B=1024, H=100].
//   r = tanh(x); x += ALPHA*(-x + r@J^T + u@b_in^T + c_x + 0.1*n)
// Parallelism: one thread per (b,h). J row cached in 100 VGPRs per thread.
// r broadcast through double-buffered LDS, 1 barrier/step.

#define TSTEPS 750
#define BATCH  1024
#define HID    100
#define B_PER_BLK 4
#define THREADS (B_PER_BLK * HID)  // 400 threads = 7 waves (last wave 16 lanes)

constexpr float ALPHA = 0.1f;   // DT/TAU = 0.001/0.01
constexpr float NSTD  = 0.1f;

__device__ __forceinline__ float ftanh(float x) {
    // tanh(x) = 1 - 2/(exp(2x)+1); handles +/-inf overflow correctly.
    float e = __expf(2.0f * x);
    return 1.0f - 2.0f * __builtin_amdgcn_rcpf(e + 1.0f);
}

__global__ __launch_bounds__(THREADS) void rnn_scan_kernel(
    const float* __restrict__ input_seq,  // [T,B,4]
    const float* __restrict__ noise,      // [T,B,H]
    const float* __restrict__ J_w,        // [H,H]
    const float* __restrict__ b_in,       // [H,4]
    const float* __restrict__ c_x,        // [H]
    float* __restrict__ states)           // [T,B,H]
{
    const int tid = threadIdx.x;
    const int b_local = tid / HID;          // 0..3 (one-time integer div)
    const int h = tid - b_local * HID;      // 0..99
    const int b = blockIdx.x * B_PER_BLK + b_local;

    // Cache J row h in registers: 25 x float4 = 100 VGPRs, compile-time indexed.
    float4 Jr[25];
    const float4* Jrow = reinterpret_cast<const float4*>(J_w + (size_t)h * HID);
#pragma unroll
    for (int i = 0; i < 25; ++i) Jr[i] = Jrow[i];

    const float4 bin = *reinterpret_cast<const float4*>(b_in + (size_t)h * 4);
    const float cx = c_x[h];

    __shared__ float r_lds[2][B_PER_BLK][HID];

    float x = 0.0f;
    r_lds[0][b_local][h] = 0.0f;  // r(x0=0) = tanh(0) = 0

    // Prefetch t=0 inputs.
    const float* uptr = input_seq + (size_t)b * 4;
    const float* nptr = noise + (size_t)b * HID + h;
    float4 u  = *reinterpret_cast<const float4*>(uptr);
    float  nz = *nptr;

    float* sptr = states + (size_t)b * HID + h;

    __syncthreads();

    for (int t = 0; t < TSTEPS; ++t) {
        // Software prefetch of next-step inputs (hides HBM latency across the step).
        const int tn = (t + 1 < TSTEPS) ? (t + 1) : t;
        float4 u_next  = *reinterpret_cast<const float4*>(uptr + (size_t)tn * BATCH * 4);
        float  nz_next = nptr[(size_t)tn * BATCH * HID];

        // Dot product: x_new[h] = sum_k r[k] * J[h,k].
        // r reads are wave-uniform addresses -> LDS broadcast, conflict-free.
        const float* rb = &r_lds[t & 1][b_local][0];
        float a0 = 0.f, a1 = 0.f, a2 = 0.f, a3 = 0.f;
#pragma unroll
        for (int i = 0; i < 25; ++i) {
            float4 r4 = *reinterpret_cast<const float4*>(rb + 4 * i);
            a0 = fmaf(r4.x, Jr[i].x, a0);
            a1 = fmaf(r4.y, Jr[i].y, a1);
            a2 = fmaf(r4.z, Jr[i].z, a2);
            a3 = fmaf(r4.w, Jr[i].w, a3);
        }
        float s = (a0 + a1) + (a2 + a3);

        float inp = u.x * bin.x + u.y * bin.y + u.z * bin.z + u.w * bin.w;
        float dx = ALPHA * (-x + s + inp + cx + NSTD * nz);
        x += dx;

        sptr[(size_t)t * BATCH * HID] = x;                 // states[t,b,h] = x_{t+1}
        r_lds[(t + 1) & 1][b_local][h] = ftanh(x);         // write next r to alt buffer

        u = u_next; nz = nz_next;
        __syncthreads();  // single barrier per step (double-buffered r_lds)
    }
}

// Readout: out[b,0] = tanh(states[0,b,:]) . wout + wb ; out[b,1] = same with states[T-1].
__global__ __launch_bounds__(64) void rnn_out_kernel(
    const float* __restrict__ states,
    const float* __restrict__ wout_w,
    const float* __restrict__ wout_b,
    float* __restrict__ out)
{
    const int b = blockIdx.x;
    const int l = threadIdx.x;  // 0..63
    const float* s0 = states + (size_t)b * HID;
    const float* sF = states + ((size_t)(TSTEPS - 1) * BATCH + b) * HID;

    float p0 = 0.f, pF = 0.f;
    if (l < HID) {
        p0 = ftanh(s0[l]) * wout_w[l];
        pF = ftanh(sF[l]) * wout_w[l];
    }
    const int l2 = l + 64;
    if (l2 < HID) {
        p0 += ftanh(s0[l2]) * wout_w[l2];
        pF += ftanh(sF[l2]) * wout_w[l2];
    }
#pragma unroll
    for (int off = 32; off > 0; off >>= 1) {
        p0 += __shfl_xor(p0, off, 64);
        pF += __shfl_xor(pF, off, 64);
    }
    if (l == 0) {
        const float wb = wout_b[0];
        out[b * 2 + 0] = p0 + wb;
        out[b * 2 + 1] = pF + wb;
    }
}

extern "C" void kernel_launch(void* const* d_in, const int* in_sizes, int n_in,
                              void* d_out, int out_size, void* d_ws, size_t ws_size,
                              hipStream_t stream) {
    const float* input_seq = (const float*)d_in[0];
    const float* noise     = (const float*)d_in[1];
    const float* J_w       = (const float*)d_in[2];
    const float* b_in      = (const float*)d_in[3];
    const float* c_x       = (const float*)d_in[4];
    const float* wout_w    = (const float*)d_in[5];
    const float* wout_b    = (const float*)d_in[6];

    float* out    = (float*)d_out;           // [B,2] first
    float* states = out + 2 * BATCH;         // then [T,B,H]

    rnn_scan_kernel<<<BATCH / B_PER_BLK, THREADS, 0, stream>>>(
        input_seq, noise, J_w, b_in, c_x, states);
    rnn_out_kernel<<<BATCH, 64, 0, stream>>>(states, wout_w, wout_b, out);
}